// Round 27
// baseline (167.822 us; speedup 1.0000x reference)
//
#include <hip/hip_runtime.h>

constexpr int Bn = 8, Cn = 3, Hn = 720, Wn = 1280;
constexpr int HW = Hn * Wn;                    // 921600 px per image
constexpr long long NTOT = (long long)Bn * Cn * HW;

constexpr int BLK  = 256;
constexpr int TH   = 16, TW = 64;              // output tile 16x64 = 1024 px
constexpr int TCOL = Wn / TW;                  // 20 tile-cols
constexpr int TPI  = (Hn / TH) * TCOL;         // 900 tiles per image
constexpr int BPX  = 180;                      // persistent blocks per XCD/image
constexpr int NWG  = 8 * BPX;                  // 1440 blocks, ALL co-resident (5.6/CU)
constexpr int TPB  = TPI / BPX;                // 5 tiles per block, exact
constexpr int PXT  = (TH * TW) / BLK;          // 4 px per thread
constexpr int WR   = 24;                       // window rows: Y-4 .. Y+19 (border-replicated)
constexpr int WC   = 84;                       // window cols: XS-4 .. XS+79
constexpr int F4W  = WC / 4;                   // 21 f4 per window row
constexpr int F4P  = WR * F4W;                 // 504 f4 slots per plane
constexpr int NF4  = 2 * F4P;                  // 1008 slots per channel (L+R)
constexpr int PSE  = 2048;                     // bf16 plane stride (elements)
constexpr int BUFE = 2 * PSE;                  // 4096 bf16 = 8 KB per channel buffer

typedef float f4 __attribute__((ext_vector_type(4)));

__device__ __forceinline__ float bf(unsigned short h) {
    return __uint_as_float((unsigned)h << 16);
}

// 4 f32 -> 4 bf16 (RNE) -> one 8B LDS write
__device__ __forceinline__ void put8(unsigned short* dst, f4 v) {
    unsigned r0, r1;
    asm("v_cvt_pk_bf16_f32 %0, %1, %2" : "=v"(r0) : "v"(v[0]), "v"(v[1]));
    asm("v_cvt_pk_bf16_f32 %0, %1, %2" : "=v"(r1) : "v"(v[2]), "v"(v[3]));
    uint2 u; u.x = r0; u.y = r1;
    *reinterpret_cast<uint2*>(dst) = u;
}

__global__ __launch_bounds__(256) void warp_loss_kernel(
        const float* __restrict__ L, const float* __restrict__ R,
        const float* __restrict__ Flm, const float* __restrict__ Frm,
        const float* __restrict__ G, float* __restrict__ part) {
    // PERSISTENT blocks: 1440 blocks (180/XCD), each processes 5 tiles of its
    // XCD's image — zero tail, zero ramp rounds, 5x fewer dispatches. Per-tile
    // body = R24 (best 86.3us): bf16 dbuf windows, stage-issued-first
    // pipeline, plain partial store (no atomic). Chunk-major tile order keeps
    // the XCD's active band in its L2.
    const int b     = blockIdx.x & 7;
    const int inner = blockIdx.x >> 3;         // [0, 180)
    const int tid   = (int)threadIdx.x;

    const float* __restrict__ Lb = L + (size_t)b * Cn * HW;
    const float* __restrict__ Rb = R + (size_t)b * Cn * HW;
    const float* __restrict__ Gb = G + (size_t)b * Cn * HW;
    const float* __restrict__ fl = Flm + (size_t)b * 2 * HW;  // [0,HW)=x, [HW,2HW)=y
    const float* __restrict__ fr = Frm + (size_t)b * 2 * HW;

    __shared__ unsigned short win[2][BUFE];    // 16 KB: two channel buffers
    __shared__ float wsum[4];

    float local = 0.f;

    for (int q = 0; q < TPB; ++q) {
        const int t    = q * BPX + inner;      // chunk-major: band q for whole XCD
        const int trow = t / TCOL;
        const int tcol = t - trow * TCOL;
        const int Y    = trow * TH;
        const int XS   = tcol * TW;

        // ---- staging slot geometry (channel-invariant within tile) ----
        int soff[4], dstE[4];
        #pragma unroll
        for (int k = 0; k < 4; ++k) {
            const int s  = min(k * BLK + tid, NF4 - 1);
            const int pl = (s >= F4P) ? 1 : 0;
            const int f  = s - pl * F4P;
            const int wr = f / F4W;
            const int c4 = f - wr * F4W;
            const int ys = min(max(Y - 4 + wr, 0), Hn - 1);
            const int xw = min(max(XS - 4 + c4 * 4, 0), Wn - 4);  // 16B-aligned
            soff[k] = ys * Wn + xw;
            dstE[k] = pl * PSE + wr * WC + c4 * 4;
        }

        // ---- tile prologue: ch0 staging + all gt + flow, taps overlap ----
        f4 s0, s1, s2, s3;
        s0 = *reinterpret_cast<const f4*>((dstE[0] >= PSE ? Rb : Lb) + soff[0]);
        s1 = *reinterpret_cast<const f4*>((dstE[1] >= PSE ? Rb : Lb) + soff[1]);
        s2 = *reinterpret_cast<const f4*>((dstE[2] >= PSE ? Rb : Lb) + soff[2]);
        s3 = *reinterpret_cast<const f4*>((dstE[3] >= PSE ? Rb : Lb) + soff[3]);

        float g[Cn][PXT];
        #pragma unroll
        for (int c = 0; c < Cn; ++c)
            #pragma unroll
            for (int k = 0; k < PXT; ++k) {
                const int i = k * BLK + tid;
                g[c][k] = Gb[(size_t)c * HW + (Y + (i >> 6)) * Wn + XS + (i & 63)];
            }

        int   aL[PXT], aR[PXT];
        float lwx[PXT], lwy[PXT], rwx[PXT], rwy[PXT];
        #pragma unroll
        for (int k = 0; k < PXT; ++k) {
            const int i = k * BLK + tid;
            const int r = i >> 6, cm = i & 63;
            const int y = Y + r, x = XS + cm;
            const int p = y * Wn + x;
            {
                const float fx = fminf(fmaxf(fl[p],      -4.0f), 3.99951171875f);
                const float fy = fminf(fmaxf(fl[HW + p], -4.0f), 3.99951171875f);
                const float xc = fminf(fmaxf((float)x + fx, 0.f), (float)(Wn - 1));
                const float yc = fminf(fmaxf((float)y + fy, 0.f), (float)(Hn - 1));
                const float x0f = floorf(xc), y0f = floorf(yc);
                lwx[k] = xc - x0f;  lwy[k] = yc - y0f;
                aL[k] = ((int)y0f - (Y - 4)) * WC + ((int)x0f - (XS - 4));
            }
            {
                const float fx = fminf(fmaxf(fr[p],      -4.0f), 3.99951171875f);
                const float fy = fminf(fmaxf(fr[HW + p], -4.0f), 3.99951171875f);
                const float xc = fminf(fmaxf((float)x + fx, 0.f), (float)(Wn - 1));
                const float yc = fminf(fmaxf((float)y + fy, 0.f), (float)(Hn - 1));
                const float x0f = floorf(xc), y0f = floorf(yc);
                rwx[k] = xc - x0f;  rwy[k] = yc - y0f;
                aR[k] = PSE + ((int)y0f - (Y - 4)) * WC + ((int)x0f - (XS - 4));
            }
        }

        // buf0 was last read at ch2 of the previous tile -> barrier guards it
        __syncthreads();
        put8(&win[0][dstE[0]], s0);
        put8(&win[0][dstE[1]], s1);
        put8(&win[0][dstE[2]], s2);
        put8(&win[0][dstE[3]], s3);
        __syncthreads();

        #pragma unroll
        for (int c = 0; c < Cn; ++c) {
            // (1) issue next channel's staging loads (span the sample phase)
            if (c < Cn - 1) {
                const float* __restrict__ Lc = Lb + (size_t)(c + 1) * HW;
                const float* __restrict__ Rc = Rb + (size_t)(c + 1) * HW;
                s0 = *reinterpret_cast<const f4*>((dstE[0] >= PSE ? Rc : Lc) + soff[0]);
                s1 = *reinterpret_cast<const f4*>((dstE[1] >= PSE ? Rc : Lc) + soff[1]);
                s2 = *reinterpret_cast<const f4*>((dstE[2] >= PSE ? Rc : Lc) + soff[2]);
                s3 = *reinterpret_cast<const f4*>((dstE[3] >= PSE ? Rc : Lc) + soff[3]);
            }

            // (2) sample channel c from win[c&1] — pure LDS + VALU
            const unsigned short* __restrict__ w = win[c & 1];
            #pragma unroll
            for (int k = 0; k < PXT; ++k) {
                const int a = aL[k];
                const float v00 = bf(w[a]),      v01 = bf(w[a + 1]);
                const float v10 = bf(w[a + WC]), v11 = bf(w[a + WC + 1]);
                float top = fmaf(lwx[k], v01 - v00, v00);
                float bot = fmaf(lwx[k], v11 - v10, v10);
                const float sL = fmaf(lwy[k], bot - top, top);
                const int a2 = aR[k];
                const float u00 = bf(w[a2]),      u01 = bf(w[a2 + 1]);
                const float u10 = bf(w[a2 + WC]), u11 = bf(w[a2 + WC + 1]);
                top = fmaf(rwx[k], u01 - u00, u00);
                bot = fmaf(rwx[k], u11 - u10, u10);
                const float sR = fmaf(rwy[k], bot - top, top);
                local += fabsf(sL - g[c][k]) + fabsf(sR - g[c][k]);
            }

            // (3) write next channel's window into the other buffer
            if (c < Cn - 1) {
                unsigned short* __restrict__ wd = win[(c + 1) & 1];
                __syncthreads();               // all waves done reading wd's old data
                put8(&wd[dstE[0]], s0);
                put8(&wd[dstE[1]], s1);
                put8(&wd[dstE[2]], s2);
                put8(&wd[dstE[3]], s3);
                __syncthreads();
            }
        }
    }

    // wave(64) shuffle reduce -> LDS cross-wave -> one plain store per block
    #pragma unroll
    for (int off = 32; off > 0; off >>= 1)
        local += __shfl_down(local, off, 64);

    const int lane = tid & 63;
    const int wid  = tid >> 6;
    if (lane == 0) wsum[wid] = local;
    __syncthreads();
    if (tid == 0)
        part[blockIdx.x] = wsum[0] + wsum[1] + wsum[2] + wsum[3];
}

__global__ __launch_bounds__(256) void finalize_kernel(
        const float* __restrict__ part, float* __restrict__ out) {
    double s = 0.0;
    for (int i = (int)threadIdx.x; i < NWG; i += 256)
        s += (double)part[i];
    #pragma unroll
    for (int off = 32; off > 0; off >>= 1)
        s += __shfl_down(s, off, 64);
    __shared__ double ws[4];
    const int lane = threadIdx.x & 63;
    const int wid  = threadIdx.x >> 6;
    if (lane == 0) ws[wid] = s;
    __syncthreads();
    if (threadIdx.x == 0)
        out[0] = (float)((ws[0] + ws[1] + ws[2] + ws[3]) / (double)NTOT);
}

extern "C" void kernel_launch(void* const* d_in, const int* in_sizes, int n_in,
                              void* d_out, int out_size, void* d_ws, size_t ws_size,
                              hipStream_t stream) {
    const float* L   = (const float*)d_in[0];
    const float* R   = (const float*)d_in[1];
    const float* flm = (const float*)d_in[2];
    const float* frm = (const float*)d_in[3];
    const float* gt  = (const float*)d_in[4];
    float* part = (float*)d_ws;                // 1440 f32 partials, all written

    warp_loss_kernel<<<NWG, BLK, 0, stream>>>(L, R, flm, frm, gt, part);
    finalize_kernel<<<1, 256, 0, stream>>>(part, (float*)d_out);
}

// Round 28
// 86.203 us; speedup vs baseline: 1.9468x; 1.9468x over previous
//
#include <hip/hip_runtime.h>

constexpr int Bn = 8, Cn = 3, Hn = 720, Wn = 1280;
constexpr int HW = Hn * Wn;                    // 921600 px per image
constexpr long long NTOT = (long long)Bn * Cn * HW;

constexpr int BLK  = 256;
constexpr int TH   = 16, TW = 64;              // output tile 16x64 = 1024 px
constexpr int TCOL = Wn / TW;                  // 20 tile-cols
constexpr int TPI  = (Hn / TH) * TCOL;         // 900 tiles per image
constexpr int NWG  = 8 * TPI;                  // 7200 blocks; bid&7 = image/XCD
constexpr int PXT  = (TH * TW) / BLK;          // 4 px per thread
constexpr int WR   = 24;                       // window rows: Y-4 .. Y+19 (border-replicated)
constexpr int WC   = 84;                       // window cols: XS-4 .. XS+79
constexpr int F4W  = WC / 4;                   // 21 f4 per window row
constexpr int F4P  = WR * F4W;                 // 504 f4 slots per plane
constexpr int NF4  = 2 * F4P;                  // 1008 slots per channel (L+R)
constexpr int PSE  = 2048;                     // bf16 plane stride (elements)
constexpr int BUFE = 2 * PSE;                  // 4096 bf16 = 8 KB per channel buffer

typedef float f4 __attribute__((ext_vector_type(4)));

__device__ __forceinline__ float bf(unsigned short h) {
    return __uint_as_float((unsigned)h << 16);
}

// 4 f32 -> 4 bf16 (RNE) -> one 8B LDS write
__device__ __forceinline__ void put8(unsigned short* dst, f4 v) {
    unsigned r0, r1;
    asm("v_cvt_pk_bf16_f32 %0, %1, %2" : "=v"(r0) : "v"(v[0]), "v"(v[1]));
    asm("v_cvt_pk_bf16_f32 %0, %1, %2" : "=v"(r1) : "v"(v[2]), "v"(v[3]));
    uint2 u; u.x = r0; u.y = r1;
    *reinterpret_cast<uint2*>(dst) = u;
}

__global__ __launch_bounds__(256) void warp_loss_kernel(
        const float* __restrict__ L, const float* __restrict__ R,
        const float* __restrict__ Flm, const float* __restrict__ Frm,
        const float* __restrict__ G, float* __restrict__ part) {
    // Best configuration (R21/R24, 86.3us): 16x64 tile, bf16 double-buffered
    // windows (16.9KB -> ~55% occupancy), stage-issued-first channel pipeline,
    // all gt loads hoisted to the prologue, plain per-block partial store
    // (NO same-address atomic — that serial chain cost 36us, R21).
    const int b    = blockIdx.x & 7;
    const int t    = blockIdx.x >> 3;          // [0, 900)
    const int trow = t / TCOL;
    const int tcol = t - trow * TCOL;
    const int Y    = trow * TH;
    const int XS   = tcol * TW;
    const int tid  = (int)threadIdx.x;

    const float* __restrict__ Lb = L + (size_t)b * Cn * HW;
    const float* __restrict__ Rb = R + (size_t)b * Cn * HW;
    const float* __restrict__ Gb = G + (size_t)b * Cn * HW;
    const float* __restrict__ fl = Flm + (size_t)b * 2 * HW;  // [0,HW)=x, [HW,2HW)=y
    const float* __restrict__ fr = Frm + (size_t)b * 2 * HW;

    __shared__ unsigned short win[2][BUFE];    // 16 KB: two channel buffers
    __shared__ float wsum[4];

    // ---- staging slot geometry (channel-invariant); tail threads clamp ----
    int soff[4], dstE[4];
    #pragma unroll
    for (int k = 0; k < 4; ++k) {
        const int s  = min(k * BLK + tid, NF4 - 1);
        const int pl = (s >= F4P) ? 1 : 0;
        const int f  = s - pl * F4P;
        const int wr = f / F4W;
        const int c4 = f - wr * F4W;
        const int ys = min(max(Y - 4 + wr, 0), Hn - 1);
        const int xw = min(max(XS - 4 + c4 * 4, 0), Wn - 4);  // 16B-aligned, in-bounds
        soff[k] = ys * Wn + xw;
        dstE[k] = pl * PSE + wr * WC + c4 * 4; // element idx; *2B is 8B-aligned
    }

    // ---- prologue: ch0 staging loads + ALL gt loads + flow, one epoch ----
    f4 s0, s1, s2, s3;
    s0 = *reinterpret_cast<const f4*>((dstE[0] >= PSE ? Rb : Lb) + soff[0]);
    s1 = *reinterpret_cast<const f4*>((dstE[1] >= PSE ? Rb : Lb) + soff[1]);
    s2 = *reinterpret_cast<const f4*>((dstE[2] >= PSE ? Rb : Lb) + soff[2]);
    s3 = *reinterpret_cast<const f4*>((dstE[3] >= PSE ? Rb : Lb) + soff[3]);

    float g[Cn][PXT];
    #pragma unroll
    for (int c = 0; c < Cn; ++c)
        #pragma unroll
        for (int k = 0; k < PXT; ++k) {
            const int i = k * BLK + tid;
            const int p = (Y + (i >> 6)) * Wn + XS + (i & 63);
            g[c][k] = Gb[(size_t)c * HW + p];
        }

    // ---- per-px tap state (channel-invariant), coalesced flow loads ----
    int   aL[PXT], aR[PXT];
    float lwx[PXT], lwy[PXT], rwx[PXT], rwy[PXT];
    #pragma unroll
    for (int k = 0; k < PXT; ++k) {
        const int i = k * BLK + tid;
        const int r = i >> 6, cm = i & 63;
        const int y = Y + r, x = XS + cm;
        const int p = y * Wn + x;
        {
            const float fx = fminf(fmaxf(fl[p],      -4.0f), 3.99951171875f);
            const float fy = fminf(fmaxf(fl[HW + p], -4.0f), 3.99951171875f);
            const float xc = fminf(fmaxf((float)x + fx, 0.f), (float)(Wn - 1));
            const float yc = fminf(fmaxf((float)y + fy, 0.f), (float)(Hn - 1));
            const float x0f = floorf(xc), y0f = floorf(yc);
            lwx[k] = xc - x0f;  lwy[k] = yc - y0f;
            aL[k] = ((int)y0f - (Y - 4)) * WC + ((int)x0f - (XS - 4));
        }
        {
            const float fx = fminf(fmaxf(fr[p],      -4.0f), 3.99951171875f);
            const float fy = fminf(fmaxf(fr[HW + p], -4.0f), 3.99951171875f);
            const float xc = fminf(fmaxf((float)x + fx, 0.f), (float)(Wn - 1));
            const float yc = fminf(fmaxf((float)y + fy, 0.f), (float)(Hn - 1));
            const float x0f = floorf(xc), y0f = floorf(yc);
            rwx[k] = xc - x0f;  rwy[k] = yc - y0f;
            aR[k] = PSE + ((int)y0f - (Y - 4)) * WC + ((int)x0f - (XS - 4));
        }
    }

    put8(&win[0][dstE[0]], s0);
    put8(&win[0][dstE[1]], s1);
    put8(&win[0][dstE[2]], s2);
    put8(&win[0][dstE[3]], s3);
    __syncthreads();

    float local = 0.f;

    for (int c = 0; c < Cn; ++c) {
        // (1) issue next channel's staging loads (span the whole sample phase)
        if (c < Cn - 1) {
            const float* __restrict__ Lc = Lb + (size_t)(c + 1) * HW;
            const float* __restrict__ Rc = Rb + (size_t)(c + 1) * HW;
            s0 = *reinterpret_cast<const f4*>((dstE[0] >= PSE ? Rc : Lc) + soff[0]);
            s1 = *reinterpret_cast<const f4*>((dstE[1] >= PSE ? Rc : Lc) + soff[1]);
            s2 = *reinterpret_cast<const f4*>((dstE[2] >= PSE ? Rc : Lc) + soff[2]);
            s3 = *reinterpret_cast<const f4*>((dstE[3] >= PSE ? Rc : Lc) + soff[3]);
        }

        // (2) sample channel c from win[c&1] — pure LDS + VALU, no vmem waits
        const unsigned short* __restrict__ w = win[c & 1];
        #pragma unroll
        for (int k = 0; k < PXT; ++k) {
            const int a = aL[k];
            const float v00 = bf(w[a]),      v01 = bf(w[a + 1]);
            const float v10 = bf(w[a + WC]), v11 = bf(w[a + WC + 1]);
            float top = fmaf(lwx[k], v01 - v00, v00);
            float bot = fmaf(lwx[k], v11 - v10, v10);
            const float sL = fmaf(lwy[k], bot - top, top);
            const int a2 = aR[k];
            const float u00 = bf(w[a2]),      u01 = bf(w[a2 + 1]);
            const float u10 = bf(w[a2 + WC]), u11 = bf(w[a2 + WC + 1]);
            top = fmaf(rwx[k], u01 - u00, u00);
            bot = fmaf(rwx[k], u11 - u10, u10);
            const float sR = fmaf(rwy[k], bot - top, top);
            local += fabsf(sL - g[c][k]) + fabsf(sR - g[c][k]);
        }

        // (3) write next channel's window into the other buffer; one barrier
        if (c < Cn - 1) {
            unsigned short* __restrict__ wd = win[(c + 1) & 1];
            put8(&wd[dstE[0]], s0);
            put8(&wd[dstE[1]], s1);
            put8(&wd[dstE[2]], s2);
            put8(&wd[dstE[3]], s3);
            __syncthreads();
        }
    }

    // wave(64) shuffle reduce -> LDS cross-wave -> ONE PLAIN STORE per block
    #pragma unroll
    for (int off = 32; off > 0; off >>= 1)
        local += __shfl_down(local, off, 64);

    const int lane = tid & 63;
    const int wid  = tid >> 6;
    if (lane == 0) wsum[wid] = local;
    __syncthreads();
    if (tid == 0)
        part[blockIdx.x] = wsum[0] + wsum[1] + wsum[2] + wsum[3];
}

__global__ __launch_bounds__(256) void finalize_kernel(
        const float* __restrict__ part, float* __restrict__ out) {
    double s = 0.0;
    for (int i = (int)threadIdx.x; i < NWG; i += 256)
        s += (double)part[i];
    #pragma unroll
    for (int off = 32; off > 0; off >>= 1)
        s += __shfl_down(s, off, 64);
    __shared__ double ws[4];
    const int lane = threadIdx.x & 63;
    const int wid  = threadIdx.x >> 6;
    if (lane == 0) ws[wid] = s;
    __syncthreads();
    if (threadIdx.x == 0)
        out[0] = (float)((ws[0] + ws[1] + ws[2] + ws[3]) / (double)NTOT);
}

extern "C" void kernel_launch(void* const* d_in, const int* in_sizes, int n_in,
                              void* d_out, int out_size, void* d_ws, size_t ws_size,
                              hipStream_t stream) {
    const float* L   = (const float*)d_in[0];
    const float* R   = (const float*)d_in[1];
    const float* flm = (const float*)d_in[2];
    const float* frm = (const float*)d_in[3];
    const float* gt  = (const float*)d_in[4];
    float* part = (float*)d_ws;                // 7200 f32 partials, all written

    warp_loss_kernel<<<NWG, BLK, 0, stream>>>(L, R, flm, frm, gt, part);
    finalize_kernel<<<1, 256, 0, stream>>>(part, (float*)d_out);
}